// Round 1
// baseline (82.346 us; speedup 1.0000x reference)
//
#include <hip/hip_runtime.h>
#include <hip/hip_bf16.h>

// Problem constants (from reference setup_inputs)
#define T1 4095     // existing stack entries
#define TT 4096     // T1 + 1
#define B  64
#define M  128
#define BM (B * M)          // 8192
#define SCAN_THREADS 256
#define EPT (TT / SCAN_THREADS)   // 16 elements per thread in scan
#define IPB 32                    // i's per block in fuse kernel
#define NCHUNK (TT / IPB)         // 128

// Kernel 1: per batch b, compute
//   totprev[i] = sum_{j>i} s[j]         (reverse exclusive cumsum over T1)
//   sn[i] = relu(s[i] - relu(u - totprev[i])) for i < T1 ; sn[T1] = d
//   tots[i] = sum_{j>i} sn[j]           (reverse exclusive cumsum over T)
//   coeff[i] = min(sn[i], relu(1 - tots[i]))
// One block per batch. Each thread owns a contiguous chunk of EPT indices.
__global__ __launch_bounds__(SCAN_THREADS) void scan_kernel(
    const float* __restrict__ s,    // [T1, B]
    const float* __restrict__ d,    // [B]
    const float* __restrict__ u,    // [B]
    float* __restrict__ sn_out,     // [TT, B]  (output 1)
    float* __restrict__ coeff)      // [TT, B]  (workspace)
{
    const int b = blockIdx.x;
    const int t = threadIdx.x;
    __shared__ float sh[SCAN_THREADS];
    __shared__ float suffix[SCAN_THREADS];

    const int base = t * EPT;
    float sv[EPT];
    float sum = 0.f;
#pragma unroll
    for (int k = 0; k < EPT; ++k) {
        int i = base + k;
        float val = (i < T1) ? s[(size_t)i * B + b] : 0.f;
        sv[k] = val;
        sum += val;
    }
    sh[t] = sum;
    __syncthreads();
    if (t == 0) {
        float acc = 0.f;
        for (int j = SCAN_THREADS - 1; j >= 0; --j) {
            float p = sh[j];
            suffix[j] = acc;   // sum over threads > j
            acc += p;
        }
    }
    __syncthreads();

    const float ub = u[b];
    float tot = suffix[t];     // sum of s over indices >= (t+1)*EPT
    float snv[EPT];
#pragma unroll
    for (int k = EPT - 1; k >= 0; --k) {
        float sval = sv[k];
        // totprev for element (base+k) is current tot
        snv[k] = fmaxf(sval - fmaxf(ub - tot, 0.f), 0.f);
        tot += sval;
    }
    if (t == SCAN_THREADS - 1) snv[EPT - 1] = d[b];  // element T1: sn = d

    __syncthreads();           // protect sh/suffix reuse
    float sum2 = 0.f;
#pragma unroll
    for (int k = 0; k < EPT; ++k) sum2 += snv[k];
    sh[t] = sum2;
    __syncthreads();
    if (t == 0) {
        float acc = 0.f;
        for (int j = SCAN_THREADS - 1; j >= 0; --j) {
            float p = sh[j];
            suffix[j] = acc;
            acc += p;
        }
    }
    __syncthreads();

    float tot2 = suffix[t];
#pragma unroll
    for (int k = EPT - 1; k >= 0; --k) {
        int i = base + k;
        float snval = snv[k];
        float c = fminf(snval, fmaxf(1.f - tot2, 0.f));
        sn_out[(size_t)i * B + b] = snval;
        coeff[(size_t)i * B + b] = c;
        tot2 += snval;
    }
}

// Kernel 2: fused Vn copy + coeff-weighted partial reduction.
// grid = (NCHUNK, BM/(256*4)); each block handles IPB i-slices for a
// 1024-float (256 thread x float4) bm range. Writes its own partial vector
// (no atomics -> deterministic).
__global__ __launch_bounds__(256) void fuse_kernel(
    const float* __restrict__ V,        // [T1, B, M]
    const float* __restrict__ v,        // [B, M]
    const float* __restrict__ coeff,    // [TT, B]
    float* __restrict__ Vn,             // [TT, B, M] (output 0)
    float* __restrict__ partials)       // [NCHUNK, BM]
{
    const int chunk = blockIdx.x;                 // i-chunk
    const int bm4 = blockIdx.y * 256 + threadIdx.x;  // float4 index in [0, BM/4)
    const int b = (bm4 * 4) / M;                  // 4 consecutive floats share b (M%4==0)

    float4 acc = make_float4(0.f, 0.f, 0.f, 0.f);
    const int i0 = chunk * IPB;
#pragma unroll 4
    for (int k = 0; k < IPB; ++k) {
        const int i = i0 + k;
        float4 val;
        if (i < T1) val = ((const float4*)(V + (size_t)i * BM))[bm4];
        else        val = ((const float4*)v)[bm4];
        ((float4*)(Vn + (size_t)i * BM))[bm4] = val;
        const float c = coeff[(size_t)i * B + b];
        acc.x += c * val.x;
        acc.y += c * val.y;
        acc.z += c * val.z;
        acc.w += c * val.w;
    }
    ((float4*)(partials + (size_t)chunk * BM))[bm4] = acc;
}

// Kernel 3: deterministic reduction of partials -> r.
__global__ __launch_bounds__(256) void reduce_kernel(
    const float* __restrict__ partials,  // [NCHUNK, BM]
    float* __restrict__ r)               // [B, M] (output 2)
{
    const int bm = blockIdx.x * 256 + threadIdx.x;
    float acc = 0.f;
#pragma unroll 8
    for (int c = 0; c < NCHUNK; ++c)
        acc += partials[(size_t)c * BM + bm];
    r[bm] = acc;
}

extern "C" void kernel_launch(void* const* d_in, const int* in_sizes, int n_in,
                              void* d_out, int out_size, void* d_ws, size_t ws_size,
                              hipStream_t stream) {
    const float* V = (const float*)d_in[0];   // [T1,B,M]
    const float* s = (const float*)d_in[1];   // [T1,B,1]
    const float* d = (const float*)d_in[2];   // [B,1]
    const float* u = (const float*)d_in[3];   // [B,1]
    const float* v = (const float*)d_in[4];   // [B,M]

    float* out = (float*)d_out;
    float* Vn = out;                                   // TT*B*M
    float* sn = out + (size_t)TT * BM;                 // TT*B
    float* r  = sn + (size_t)TT * B;                   // B*M

    float* coeff = (float*)d_ws;                       // TT*B floats
    float* partials = coeff + (size_t)TT * B;          // NCHUNK*BM floats

    scan_kernel<<<B, SCAN_THREADS, 0, stream>>>(s, d, u, sn, coeff);
    fuse_kernel<<<dim3(NCHUNK, BM / (256 * 4)), 256, 0, stream>>>(V, v, coeff, Vn, partials);
    reduce_kernel<<<BM / 256, 256, 0, stream>>>(partials, r);
}

// Round 2
// 71.400 us; speedup vs baseline: 1.1533x; 1.1533x over previous
//
#include <hip/hip_runtime.h>
#include <hip/hip_bf16.h>

// Problem constants (from reference setup_inputs)
#define T1 4095     // existing stack entries
#define TT 4096     // T1 + 1
#define B  64
#define M  128
#define BM (B * M)                // 8192
#define SCAN_THREADS 256
#define EPT (TT / SCAN_THREADS)   // 16 elements per thread in scan
#define IPB 32                    // i's per block in fuse kernel
#define NCHUNK (TT / IPB)         // 128

typedef float f32x4 __attribute__((ext_vector_type(4)));

// Kernel 1: per batch b (one block per b), compute
//   totprev[i] = sum_{j>i} s[j]
//   sn[i] = relu(s[i] - relu(u - totprev[i])) for i < T1 ; sn[T1] = d
//   tots[i] = sum_{j>i} sn[j]
//   coeff[i] = min(sn[i], relu(1 - tots[i]))
// sn written to output layout [TT,B] (strided; L2 merges columns).
// coeff written TRANSPOSED [B,TT] (coalesced) for fast re-read in fuse.
__global__ __launch_bounds__(SCAN_THREADS) void scan_kernel(
    const float* __restrict__ s,    // [T1, B]
    const float* __restrict__ d,    // [B]
    const float* __restrict__ u,    // [B]
    float* __restrict__ sn_out,     // [TT, B]  (output 1)
    float* __restrict__ coeffT)     // [B, TT]  (workspace, transposed)
{
    const int b = blockIdx.x;
    const int t = threadIdx.x;
    __shared__ float sh[SCAN_THREADS];

    const int base = t * EPT;
    float sv[EPT];
    float sum = 0.f;
#pragma unroll
    for (int k = 0; k < EPT; ++k) {
        int i = base + k;
        float val = (i < T1) ? s[(size_t)i * B + b] : 0.f;
        sv[k] = val;
        sum += val;
    }
    const float mysum = sum;
    sh[t] = sum;
    __syncthreads();
    // Parallel inclusive suffix scan (Hillis-Steele), 8 steps.
#pragma unroll
    for (int dstep = 1; dstep < SCAN_THREADS; dstep <<= 1) {
        float add = (t + dstep < SCAN_THREADS) ? sh[t + dstep] : 0.f;
        __syncthreads();
        sh[t] += add;
        __syncthreads();
    }
    float suffix = sh[t] - mysum;   // sum over threads > t

    const float ub = u[b];
    float tot = suffix;
    float snv[EPT];
#pragma unroll
    for (int k = EPT - 1; k >= 0; --k) {
        float sval = sv[k];
        snv[k] = fmaxf(sval - fmaxf(ub - tot, 0.f), 0.f);
        tot += sval;
    }
    if (t == SCAN_THREADS - 1) snv[EPT - 1] = d[b];  // element T1: sn = d

    float sum2 = 0.f;
#pragma unroll
    for (int k = 0; k < EPT; ++k) sum2 += snv[k];
    __syncthreads();           // protect sh reuse
    sh[t] = sum2;
    __syncthreads();
#pragma unroll
    for (int dstep = 1; dstep < SCAN_THREADS; dstep <<= 1) {
        float add = (t + dstep < SCAN_THREADS) ? sh[t + dstep] : 0.f;
        __syncthreads();
        sh[t] += add;
        __syncthreads();
    }
    float suffix2 = sh[t] - sum2;

    float tot2 = suffix2;
    float cv[EPT];
#pragma unroll
    for (int k = EPT - 1; k >= 0; --k) {
        float snval = snv[k];
        cv[k] = fminf(snval, fmaxf(1.f - tot2, 0.f));
        tot2 += snval;
    }
    // sn: output layout (strided by 256B; small, L2-merged)
#pragma unroll
    for (int k = 0; k < EPT; ++k)
        sn_out[(size_t)(base + k) * B + b] = snv[k];
    // coeffT: coalesced float4 stores
    f32x4* cT4 = (f32x4*)(coeffT + (size_t)b * TT + base);
#pragma unroll
    for (int q = 0; q < EPT / 4; ++q) {
        f32x4 cc = { cv[4*q+0], cv[4*q+1], cv[4*q+2], cv[4*q+3] };
        cT4[q] = cc;
    }
}

// Kernel 2: fused Vn copy + coeff-weighted partial reduction.
// grid = (8 bm-tiles, NCHUNK chunks). Coeffs preloaded (8 x float4), hot loop
// is branch-free nontemporal 16B load + store + 4 FMA.
__global__ __launch_bounds__(256) void fuse_kernel(
    const float* __restrict__ V,        // [T1, B, M]
    const float* __restrict__ v,        // [B, M]
    const float* __restrict__ coeffT,   // [B, TT]
    float* __restrict__ Vn,             // [TT, B, M] (output 0)
    float* __restrict__ partials)       // [NCHUNK, BM]
{
    const int bmTile = blockIdx.x;                   // 0..7
    const int chunk  = blockIdx.y;                   // 0..NCHUNK-1
    const int bm4 = bmTile * 256 + threadIdx.x;      // float4 index in [0, BM/4)
    const int b = bm4 >> 5;                          // (bm4*4)/M, M=128
    const int i0 = chunk * IPB;

    // Preload this thread's 32 coefficients (contiguous in coeffT).
    float c[IPB];
    const f32x4* cp = (const f32x4*)(coeffT + (size_t)b * TT + i0);
#pragma unroll
    for (int q = 0; q < IPB / 4; ++q) {
        f32x4 cc = cp[q];
        c[4*q+0] = cc.x; c[4*q+1] = cc.y; c[4*q+2] = cc.z; c[4*q+3] = cc.w;
    }

    f32x4 acc = {0.f, 0.f, 0.f, 0.f};
    const f32x4* Vp  = (const f32x4*)V;
    f32x4*       Vnp = (f32x4*)Vn;

    if (chunk != NCHUNK - 1) {
#pragma unroll 8
        for (int k = 0; k < IPB; ++k) {
            const size_t idx = (size_t)(i0 + k) * (BM / 4) + bm4;
            f32x4 val = __builtin_nontemporal_load(&Vp[idx]);
            __builtin_nontemporal_store(val, &Vnp[idx]);
            acc += c[k] * val;
        }
    } else {
#pragma unroll 8
        for (int k = 0; k < IPB - 1; ++k) {
            const size_t idx = (size_t)(i0 + k) * (BM / 4) + bm4;
            f32x4 val = __builtin_nontemporal_load(&Vp[idx]);
            __builtin_nontemporal_store(val, &Vnp[idx]);
            acc += c[k] * val;
        }
        // i = T1: push v
        f32x4 val = ((const f32x4*)v)[bm4];
        __builtin_nontemporal_store(val, &Vnp[(size_t)T1 * (BM / 4) + bm4]);
        acc += c[IPB - 1] * val;
    }
    ((f32x4*)partials)[(size_t)chunk * (BM / 4) + bm4] = acc;
}

// Kernel 3: deterministic reduction of partials -> r. 128 blocks x 1 wave.
__global__ __launch_bounds__(64) void reduce_kernel(
    const float* __restrict__ partials,  // [NCHUNK, BM]
    float* __restrict__ r)               // [B, M] (output 2)
{
    const int bm = blockIdx.x * 64 + threadIdx.x;
    float acc = 0.f;
#pragma unroll 8
    for (int ch = 0; ch < NCHUNK; ++ch)
        acc += partials[(size_t)ch * BM + bm];
    r[bm] = acc;
}

extern "C" void kernel_launch(void* const* d_in, const int* in_sizes, int n_in,
                              void* d_out, int out_size, void* d_ws, size_t ws_size,
                              hipStream_t stream) {
    const float* V = (const float*)d_in[0];   // [T1,B,M]
    const float* s = (const float*)d_in[1];   // [T1,B,1]
    const float* d = (const float*)d_in[2];   // [B,1]
    const float* u = (const float*)d_in[3];   // [B,1]
    const float* v = (const float*)d_in[4];   // [B,M]

    float* out = (float*)d_out;
    float* Vn = out;                                   // TT*B*M
    float* sn = out + (size_t)TT * BM;                 // TT*B
    float* r  = sn + (size_t)TT * B;                   // B*M

    float* coeffT   = (float*)d_ws;                    // B*TT floats (transposed)
    float* partials = coeffT + (size_t)B * TT;         // NCHUNK*BM floats

    scan_kernel<<<B, SCAN_THREADS, 0, stream>>>(s, d, u, sn, coeffT);
    fuse_kernel<<<dim3(8, NCHUNK), 256, 0, stream>>>(V, v, coeffT, Vn, partials);
    reduce_kernel<<<BM / 64, 64, 0, stream>>>(partials, r);
}